// Round 11
// baseline (367.860 us; speedup 1.0000x reference)
//
#include <hip/hip_runtime.h>
#include <math.h>

#define HEADS 8
#define DK 32
#define B_ 4
#define C_ 256
#define NVOX 1728   // 12*12*12
#define DE 64       // effective head dim: Q'=[q;pos], K'=[k;q]
#define PITCH 72    // attn LDS pitch (shorts): 144 B rows
#define XPITCH 136  // fproj x-chunk LDS pitch (shorts): 272 B rows
#define CPITCH 36   // fproj cbuf pitch (floats)
#define LOG2E 1.44269504088896f

typedef _Float16 f16x8 __attribute__((ext_vector_type(8)));
typedef __fp16 fp16x2 __attribute__((ext_vector_type(2)));
typedef float f32x16 __attribute__((ext_vector_type(16)));

__device__ inline float h2f(short s) {
    _Float16 h = *(_Float16*)&s;
    return (float)h;
}
__device__ inline f32x16 mfma32h(f16x8 a, f16x8 b, f32x16 c) {
    return __builtin_amdgcn_mfma_f32_32x32x16_f16(a, b, c, 0, 0, 0);
}

union HF8 { _Float16 h[8]; f16x8 f; uint4 v; };

// ---------------------------------------------------------------------------
// Mega-fused projection: x fp32 (in-kernel transpose+cvt), w fp32 (in-reg
// cvt), pos fused in epilogue.  out: Qf (with pos upper), Kf ([k;q]), Vf.
// grid (27, HEADS, B_), block 384 = 6 waves = 3 mats x 2 n-halves.
// ---------------------------------------------------------------------------
struct FS {
    union {
        short xs[64 * XPITCH];       // f16 x-chunk, [n][c_local<128]
        float cbuf[3][64][CPITCH];   // epilogue C staging [mat][n][o]
    } u;
};

__global__ __launch_bounds__(384, 3)
void fproj_kernel(const float* __restrict__ x,
                  const float* __restrict__ wq, const float* __restrict__ wk,
                  const float* __restrict__ wv,
                  const float* __restrict__ bq, const float* __restrict__ bk,
                  const float* __restrict__ bv,
                  const float* __restrict__ rel_d, const float* __restrict__ rel_h,
                  const float* __restrict__ rel_w,
                  short* __restrict__ Qf, short* __restrict__ Kf,
                  short* __restrict__ Vf) {
    __shared__ FS sm;
    int nb = blockIdx.x * 64, h = blockIdx.y, b = blockIdx.z;
    int bh = b * HEADS + h;
    int t = threadIdx.x;
    int w = t >> 6, l = t & 63, ln = l & 31, hv = l >> 5;
    int mat = w >> 1, nh = w & 1;

    const float* xb = x + (size_t)b * C_ * NVOX + nb;   // [c][n-slice]
    const float* wsel = (mat == 0) ? wq : (mat == 1) ? wk : wv;
    const float* wrow = wsel + (size_t)(h * DK + ln) * C_;
    int xrow = (nh * 32 + ln) * XPITCH;

    f32x16 acc;
    #pragma unroll
    for (int r = 0; r < 16; r++) acc[r] = 0.f;

    #pragma unroll 1
    for (int ch = 0; ch < 2; ch++) {
        // ---- W fragments for this chunk: fp32 -> f16 in registers ----
        f16x8 wfr[8];
        #pragma unroll
        for (int ks = 0; ks < 8; ks++) {
            const float* wp = wrow + ch * 128 + ks * 16 + hv * 8;
            float4 a4 = *(const float4*)&wp[0];
            float4 b4 = *(const float4*)&wp[4];
            HF8 hh;
            hh.h[0] = (_Float16)a4.x; hh.h[1] = (_Float16)a4.y;
            hh.h[2] = (_Float16)a4.z; hh.h[3] = (_Float16)a4.w;
            hh.h[4] = (_Float16)b4.x; hh.h[5] = (_Float16)b4.y;
            hh.h[6] = (_Float16)b4.z; hh.h[7] = (_Float16)b4.w;
            wfr[ks] = hh.f;
        }

        // ---- stage x chunk: load [c][n] fp32 coalesced, write transposed f16
        __syncthreads();   // previous chunk fully consumed
        for (int e = t; e < 2048; e += 384) {
            int cl = e >> 4;              // 0..127 (c within chunk)
            int n4 = (e & 15) * 4;        // 0..60
            float4 v = *(const float4*)&xb[(size_t)(ch * 128 + cl) * NVOX + n4];
            _Float16 h0 = (_Float16)v.x, h1 = (_Float16)v.y,
                     h2 = (_Float16)v.z, h3 = (_Float16)v.w;
            sm.u.xs[(n4 + 0) * XPITCH + cl] = *(short*)&h0;
            sm.u.xs[(n4 + 1) * XPITCH + cl] = *(short*)&h1;
            sm.u.xs[(n4 + 2) * XPITCH + cl] = *(short*)&h2;
            sm.u.xs[(n4 + 3) * XPITCH + cl] = *(short*)&h3;
        }
        __syncthreads();

        #pragma unroll
        for (int ks = 0; ks < 8; ks++) {
            f16x8 bfr = *(const f16x8*)&sm.u.xs[xrow + ks * 16 + hv * 8];
            acc = mfma32h(wfr[ks], bfr, acc);
        }
    }
    __syncthreads();   // x tile dead; reuse as cbuf

    const float* bias = (mat == 0) ? bq : (mat == 1) ? bk : bv;
    int ncol = nh * 32 + ln;
    #pragma unroll
    for (int q2 = 0; q2 < 4; q2++) {
        float4 cv;
        float* cvp = (float*)&cv;
        #pragma unroll
        for (int m = 0; m < 4; m++) {
            int o_loc = 8 * q2 + 4 * hv + m;
            cvp[m] = acc[4 * q2 + m] + bias[h * DK + o_loc];
        }
        *(float4*)&sm.u.cbuf[mat][ncol][8 * q2 + 4 * hv] = cv;
    }
    __syncthreads();

    if (t < 256) {
        // ---- readout q/k ----
        {
            int n = t >> 2, ddg = (t & 3) * 8;
            size_t rowoff = ((size_t)bh * NVOX + nb + n) * DE;
            HF8 qh, kh;
            #pragma unroll
            for (int j = 0; j < 8; j++) {
                qh.h[j] = (_Float16)sm.u.cbuf[0][n][ddg + j];
                kh.h[j] = (_Float16)sm.u.cbuf[1][n][ddg + j];
            }
            *(uint4*)&Qf[rowoff + ddg] = qh.v;
            *(uint4*)&Kf[rowoff + ddg] = kh.v;
            *(uint4*)&Kf[rowoff + DK + ddg] = qh.v;   // K' upper = q
        }
        // ---- readout v ----
        {
            int d = t >> 3, ng = (t & 7) * 8;
            HF8 vv;
            #pragma unroll
            for (int j = 0; j < 8; j++)
                vv.h[j] = (_Float16)sm.u.cbuf[2][ng + j][d];
            *(uint4*)&Vf[((size_t)bh * DK + d) * NVOX + nb + ng] = vv.v;
        }
        // ---- pos -> Q' upper half [32:64) ----
        {
            int nl = t & 63, dd0 = (t >> 6) * 8;
            int n = nb + nl;
            int di = n / 144, wi = (n / 12) % 12, hi = n % 12;
            HF8 ph;
            #pragma unroll
            for (int o = 0; o < 8; o++) {
                int hd = h * DK + dd0 + o;
                ph.h[o] = (_Float16)(rel_d[hd * 12 + di] + rel_w[hd * 12 + wi] +
                                     rel_h[hd * 12 + hi]);
            }
            *(uint4*)&Qf[((size_t)bh * NVOX + n) * DE + DK + dd0] = ph.v;
        }
    }
}

// ---------------------------------------------------------------------------
// Flash attention + fused 2-way merge.  32x32x16 f16 MFMA, S^T orientation,
// i-tile 64 (2 waves), j-split 2.  grid (54, HEADS, B_), block 128.
// Last-finishing block of each (bh, i-tile) pair merges and writes out.
// ---------------------------------------------------------------------------
struct SMem {
    short K[64][PITCH];
    short V[DK][PITCH];
    short P[64][PITCH];
};

__global__ __launch_bounds__(128, 3)
void attn_kernel(const short* __restrict__ Qf, const short* __restrict__ Kf,
                 const short* __restrict__ Vf,
                 short* __restrict__ wsO, float* __restrict__ wsM,
                 float* __restrict__ wsL, int* __restrict__ cnt,
                 float* __restrict__ out) {
    __shared__ SMem sm;
    __shared__ int lastFlag;
    int bx = blockIdx.x;
    int it = bx >> 1, jp = bx & 1;
    int h = blockIdx.y, b = blockIdx.z;
    int bh = b * HEADS + h;
    int t = threadIdx.x;
    int w  = t >> 6;
    int l  = t & 63;
    int ln = l & 31;
    int hv = l >> 5;
    int i_loc  = w * 32 + ln;
    int i_glob = it * 64 + i_loc;

    const short* Qp = Qf + (size_t)bh * NVOX * DE;
    const short* Kp = Kf + (size_t)bh * NVOX * DE;
    const short* Vp = Vf + (size_t)bh * DK * NVOX;

    f16x8 qf[4];
    #pragma unroll
    for (int ks = 0; ks < 4; ks++)
        qf[ks] = *(const f16x8*)&Qp[(size_t)i_glob * DE + ks * 16 + hv * 8];

    float mL = -INFINITY;
    float lsum = 0.f;
    f32x16 O;
    #pragma unroll
    for (int r = 0; r < 16; r++) O[r] = 0.f;

    int jt0 = jp ? 14 : 0, jt1 = jp ? 27 : 14;
    #pragma unroll 1
    for (int jt = jt0; jt < jt1; jt++) {
        int jb = jt * 64;
        __syncthreads();
        for (int e = t; e < 512; e += 128) {
            int row = e >> 3, c = (e & 7) * 8;
            *(uint4*)&sm.K[row][c] = *(const uint4*)&Kp[(size_t)(jb + row) * DE + c];
        }
        for (int e = t; e < 256; e += 128) {
            int d = e >> 3, c = (e & 7) * 8;
            *(uint4*)&sm.V[d][c] = *(const uint4*)&Vp[(size_t)d * NVOX + jb + c];
        }
        __syncthreads();

        // ---- S^T: two 32x32 j-subtiles ----
        f32x16 sc[2];
        #pragma unroll
        for (int js = 0; js < 2; js++) {
            f32x16 s;
            #pragma unroll
            for (int r = 0; r < 16; r++) s[r] = 0.f;
            #pragma unroll
            for (int ks = 0; ks < 4; ks++) {
                f16x8 kfr = *(const f16x8*)&sm.K[js * 32 + ln][ks * 16 + hv * 8];
                s = mfma32h(kfr, qf[ks], s);
            }
            sc[js] = s;
        }

        // ---- online softmax ----
        float mx = sc[0][0];
        #pragma unroll
        for (int js = 0; js < 2; js++)
            #pragma unroll
            for (int r = 0; r < 16; r++) mx = fmaxf(mx, sc[js][r]);
        mx = fmaxf(mx, __shfl_xor(mx, 32));
        float mLn = fmaxf(mL, mx * LOG2E);
        float alpha = exp2f(mL - mLn);
        mL = mLn;
        float ps = 0.f;
        #pragma unroll
        for (int js = 0; js < 2; js++)
            #pragma unroll
            for (int r = 0; r < 16; r++) {
                float p = exp2f(fmaf(sc[js][r], LOG2E, -mLn));
                sc[js][r] = p;
                ps += p;
            }
        ps += __shfl_xor(ps, 32);
        lsum = lsum * alpha + ps;

        // ---- P: C-layout -> LDS [i][j] f16, packed cvt ----
        #pragma unroll
        for (int js = 0; js < 2; js++)
            #pragma unroll
            for (int g = 0; g < 4; g++) {
                union { fp16x2 h2[2]; uint2 v; } pk;
                pk.h2[0] = __builtin_amdgcn_cvt_pkrtz(sc[js][4 * g + 0], sc[js][4 * g + 1]);
                pk.h2[1] = __builtin_amdgcn_cvt_pkrtz(sc[js][4 * g + 2], sc[js][4 * g + 3]);
                *(uint2*)&sm.P[i_loc][js * 32 + g * 8 + hv * 4] = pk.v;
            }

        // ---- O^T += Vt * P ----
        #pragma unroll
        for (int r = 0; r < 16; r++) O[r] *= alpha;
        #pragma unroll
        for (int ks = 0; ks < 4; ks++) {
            f16x8 va = *(const f16x8*)&sm.V[ln][ks * 16 + hv * 8];
            f16x8 pb = *(const f16x8*)&sm.P[i_loc][ks * 16 + hv * 8];
            O = mfma32h(va, pb, O);
        }
    }

    // ---- round own O through f16 (merge-order-independent result) ----
    #pragma unroll
    for (int r = 0; r < 16; r++) {
        _Float16 t16 = (_Float16)O[r];
        O[r] = (float)t16;
    }

    // ---- write partial (f16 O + fp32 m,l) ----
    short* Op = wsO + ((size_t)jp * (B_ * HEADS) + bh) * DK * NVOX;
    #pragma unroll
    for (int r = 0; r < 16; r++) {
        int d = (r & 3) + 8 * (r >> 2) + 4 * hv;
        _Float16 oh = (_Float16)O[r];
        Op[(size_t)d * NVOX + i_glob] = *(short*)&oh;
    }
    if (hv == 0) {
        size_t mo = ((size_t)jp * (B_ * HEADS) + bh) * NVOX + i_glob;
        wsM[mo] = mL;
        wsL[mo] = lsum;
    }

    // ---- elect merger: last block of the (bh, it) pair ----
    __threadfence();
    __syncthreads();
    if (t == 0) lastFlag = atomicAdd(&cnt[bh * 27 + it], 1);
    __syncthreads();
    if (lastFlag == 0) return;
    __threadfence();   // acquire: partner's partial now visible

    int jpo = jp ^ 1;
    size_t moo = ((size_t)jpo * (B_ * HEADS) + bh) * NVOX + i_glob;
    float mo_ = wsM[moo];
    float lo_ = wsL[moo];
    float m = fmaxf(mL, mo_);
    float a_s = exp2f(mL - m), a_o = exp2f(mo_ - m);
    float inv = 1.f / (a_s * lsum + a_o * lo_);
    const short* Po = wsO + ((size_t)jpo * (B_ * HEADS) + bh) * DK * NVOX;
    float* outp = out + (size_t)bh * DK * NVOX;
    #pragma unroll
    for (int r = 0; r < 16; r++) {
        int d = (r & 3) + 8 * (r >> 2) + 4 * hv;
        float oo = h2f(Po[(size_t)d * NVOX + i_glob]);
        outp[(size_t)d * NVOX + i_glob] = (a_s * O[r] + a_o * oo) * inv;
    }
}

// ---------------------------------------------------------------------------
extern "C" void kernel_launch(void* const* d_in, const int* in_sizes, int n_in,
                              void* d_out, int out_size, void* d_ws, size_t ws_size,
                              hipStream_t stream) {
    const float* x     = (const float*)d_in[0];
    const float* wq    = (const float*)d_in[1];
    const float* bq    = (const float*)d_in[2];
    const float* wk    = (const float*)d_in[3];
    const float* bk    = (const float*)d_in[4];
    const float* wv    = (const float*)d_in[5];
    const float* bv    = (const float*)d_in[6];
    const float* rel_d = (const float*)d_in[7];
    const float* rel_h = (const float*)d_in[8];
    const float* rel_w = (const float*)d_in[9];
    float* out = (float*)d_out;

    size_t qksz = (size_t)B_ * HEADS * NVOX * DE;        // 3,538,944
    size_t vsz  = (size_t)B_ * HEADS * DK * NVOX;        // 1,769,472
    size_t mlsz = (size_t)B_ * HEADS * NVOX;             // 55,296
    short* Qf  = (short*)d_ws;
    short* Kf  = Qf + qksz;
    short* Vf  = Kf + qksz;
    short* wsO = Vf + vsz;                               // 2*vsz shorts (f16)
    float* wsM = (float*)(wsO + 2 * vsz);                // 2*mlsz floats
    float* wsL = wsM + 2 * mlsz;
    int*   cnt = (int*)(wsL + 2 * mlsz);                 // 864 ints

    hipMemsetAsync(cnt, 0, (size_t)B_ * HEADS * 27 * sizeof(int), stream);
    fproj_kernel<<<dim3(NVOX / 64, HEADS, B_), dim3(384), 0, stream>>>(
        x, wq, wk, wv, bq, bk, bv, rel_d, rel_h, rel_w, Qf, Kf, Vf);
    attn_kernel<<<dim3(2 * NVOX / 64, HEADS, B_), dim3(128), 0, stream>>>(
        Qf, Kf, Vf, wsO, wsM, wsL, cnt, out);
}

// Round 12
// 187.589 us; speedup vs baseline: 1.9610x; 1.9610x over previous
//
#include <hip/hip_runtime.h>
#include <math.h>

#define HEADS 8
#define DK 32
#define B_ 4
#define C_ 256
#define NVOX 1728   // 12*12*12
#define DE 64       // effective head dim: Q'=[q;pos], K'=[k;q]
#define PITCH 72    // attn LDS pitch (shorts): 144 B rows
#define XPITCH 136  // fproj x-chunk LDS pitch (shorts)
#define CPITCH 36   // fproj cbuf pitch (floats)
#define LOG2E 1.44269504088896f

typedef _Float16 f16x8 __attribute__((ext_vector_type(8)));
typedef __fp16 fp16x2 __attribute__((ext_vector_type(2)));
typedef float f32x16 __attribute__((ext_vector_type(16)));

__device__ inline float h2f(short s) {
    _Float16 h = *(_Float16*)&s;
    return (float)h;
}
__device__ inline f32x16 mfma32h(f16x8 a, f16x8 b, f32x16 c) {
    return __builtin_amdgcn_mfma_f32_32x32x16_f16(a, b, c, 0, 0, 0);
}

union H8 { _Float16 h[8]; uint4 v; };
union H4 { _Float16 h[4]; uint2 v; };

// ---------------------------------------------------------------------------
// Fused prep: [0,192) w->f16 x4 | [192,624) x transpose->f16 | [624,1488) pos
// ---------------------------------------------------------------------------
__global__ __launch_bounds__(256)
void prep_kernel(const float* __restrict__ x,
                 const float* __restrict__ wq, const float* __restrict__ wk,
                 const float* __restrict__ wv,
                 const float* __restrict__ rel_d, const float* __restrict__ rel_h,
                 const float* __restrict__ rel_w,
                 short* __restrict__ wf, short* __restrict__ xf,
                 short* __restrict__ Qf) {
    __shared__ float tile[64][65];
    int bid = blockIdx.x;
    int t = threadIdx.x;

    if (bid < 192) {                       // ---- weights -> f16 (x4) ----
        int idx = (bid * 256 + t) * 4;     // 3*65536 total
        int m = idx >> 16;
        const float* w = (m == 0) ? wq : (m == 1) ? wk : wv;
        float4 v = *(const float4*)&w[idx & 65535];
        H4 hh;
        hh.h[0] = (_Float16)v.x; hh.h[1] = (_Float16)v.y;
        hh.h[2] = (_Float16)v.z; hh.h[3] = (_Float16)v.w;
        *(uint2*)&wf[idx] = hh.v;
    } else if (bid < 624) {                // ---- x[b][c][n] -> xf[b][n][c] ----
        int q = bid - 192;                 // 432 blocks: (27, 4, 4)
        int nb = (q % 27) * 64;
        int c0 = ((q / 27) % 4) * 64;
        int b  = q / 108;
        const float* xb = x + (size_t)b * C_ * NVOX;
        for (int e = t; e < 4096; e += 256) {
            int ci = e >> 6, nl = e & 63;
            tile[ci][nl] = xb[(size_t)(c0 + ci) * NVOX + nb + nl];
        }
        __syncthreads();
        for (int e = t; e < 512; e += 256) {
            int n = e >> 3, cg = (e & 7) * 8;
            H8 hi;
            #pragma unroll
            for (int j = 0; j < 8; j++) hi.h[j] = (_Float16)tile[cg + j][n];
            *(uint4*)&xf[((size_t)b * NVOX + nb + n) * C_ + c0 + cg] = hi.v;
        }
    } else {                               // ---- pos -> Q' upper half ----
        int q = bid - 624;                 // 864 blocks: (27, 8, 4)
        int nb = (q % 27) * 64;
        int h  = (q / 27) % 8;
        int b  = q / 216;
        int bh = b * HEADS + h;
        int nl = t & 63, dd0 = (t >> 6) * 8;
        int n = nb + nl;
        int di = n / 144, wi = (n / 12) % 12, hi = n % 12;
        H8 ph;
        #pragma unroll
        for (int o = 0; o < 8; o++) {
            int hd = h * DK + dd0 + o;
            ph.h[o] = (_Float16)(rel_d[hd * 12 + di] + rel_w[hd * 12 + wi] +
                                 rel_h[hd * 12 + hi]);
        }
        *(uint4*)&Qf[((size_t)bh * NVOX + n) * DE + DK + dd0] = ph.v;
    }
}

// ---------------------------------------------------------------------------
// MFMA projection (f16), K chunked 2x128.  grid (27, HEADS, B_), block 384.
// ---------------------------------------------------------------------------
struct FS {
    union {
        short xs[64 * XPITCH];
        float cbuf[3][64][CPITCH];
    } u;
};

__global__ __launch_bounds__(384, 4)
void fproj_kernel(const short* __restrict__ xf, const short* __restrict__ wf,
                  const float* __restrict__ bq, const float* __restrict__ bk,
                  const float* __restrict__ bv,
                  short* __restrict__ Qf, short* __restrict__ Kf,
                  short* __restrict__ Vf) {
    __shared__ FS sm;
    int nb = blockIdx.x * 64, h = blockIdx.y, b = blockIdx.z;
    int bh = b * HEADS + h;
    int t = threadIdx.x;
    int w = t >> 6, l = t & 63, ln = l & 31, hv = l >> 5;
    int mat = w >> 1, nh = w & 1;

    const short* xb = xf + ((size_t)b * NVOX + nb) * C_;
    const short* wA = wf + ((size_t)mat * C_ + h * DK + ln) * C_;
    int xrow = (nh * 32 + ln) * XPITCH;

    f32x16 acc;
    #pragma unroll
    for (int r = 0; r < 16; r++) acc[r] = 0.f;

    #pragma unroll 1
    for (int ch = 0; ch < 2; ch++) {
        __syncthreads();
        for (int e = t; e < 1024; e += 384) {
            int row = e >> 4, c8 = (e & 15) * 8;
            *(uint4*)&sm.u.xs[row * XPITCH + c8] =
                *(const uint4*)&xb[row * C_ + ch * 128 + c8];
        }
        __syncthreads();
        #pragma unroll 4
        for (int ks = 0; ks < 8; ks++) {
            int kl_ = ks * 16 + hv * 8;
            f16x8 a = *(const f16x8*)&wA[ch * 128 + kl_];
            f16x8 bfr = *(const f16x8*)&sm.u.xs[xrow + kl_];
            acc = mfma32h(a, bfr, acc);
        }
    }
    __syncthreads();   // x tile dead; reuse as cbuf

    const float* bias = (mat == 0) ? bq : (mat == 1) ? bk : bv;
    int ncol = nh * 32 + ln;
    #pragma unroll
    for (int q2 = 0; q2 < 4; q2++) {
        float4 cv;
        float* cvp = (float*)&cv;
        #pragma unroll
        for (int m = 0; m < 4; m++) {
            int o_loc = 8 * q2 + 4 * hv + m;
            cvp[m] = acc[4 * q2 + m] + bias[h * DK + o_loc];
        }
        *(float4*)&sm.u.cbuf[mat][ncol][8 * q2 + 4 * hv] = cv;
    }
    __syncthreads();

    if (t < 256) {                          // ---- readout q/k ----
        int n = t >> 2, ddg = (t & 3) * 8;
        size_t rowoff = ((size_t)bh * NVOX + nb + n) * DE;
        H8 qh, kh;
        #pragma unroll
        for (int j = 0; j < 8; j++) {
            qh.h[j] = (_Float16)sm.u.cbuf[0][n][ddg + j];
            kh.h[j] = (_Float16)sm.u.cbuf[1][n][ddg + j];
        }
        *(uint4*)&Qf[rowoff + ddg] = qh.v;
        *(uint4*)&Kf[rowoff + ddg] = kh.v;
        *(uint4*)&Kf[rowoff + DK + ddg] = qh.v;   // K' upper = q
    }
    if (t < 256) {                          // ---- readout v ----
        int d = t >> 3, ng = (t & 7) * 8;
        H8 vv;
        #pragma unroll
        for (int j = 0; j < 8; j++)
            vv.h[j] = (_Float16)sm.u.cbuf[2][ng + j][d];
        *(uint4*)&Vf[((size_t)bh * DK + d) * NVOX + nb + ng] = vv.v;
    }
}

// ---------------------------------------------------------------------------
// Flash attention partial: 32x32x16 f16 MFMA, S^T orientation, i-tile 64
// (2 waves), j-split 2, REGISTER-PREFETCH pipelined staging.
// grid (54, HEADS, B_), block 128.  LDS 23.0 KB -> 6 blocks/CU.
// ---------------------------------------------------------------------------
struct SMem {
    short K[64][PITCH];
    short V[DK][PITCH];
    short P[64][PITCH];
};

__global__ __launch_bounds__(128, 3)
void attn_kernel(const short* __restrict__ Qf, const short* __restrict__ Kf,
                 const short* __restrict__ Vf,
                 short* __restrict__ wsO, float* __restrict__ wsM,
                 float* __restrict__ wsL) {
    __shared__ SMem sm;
    int bx = blockIdx.x;
    int it = bx >> 1, jp = bx & 1;
    int h = blockIdx.y, b = blockIdx.z;
    int bh = b * HEADS + h;
    int t = threadIdx.x;
    int w  = t >> 6;
    int l  = t & 63;
    int ln = l & 31;
    int hv = l >> 5;
    int i_loc  = w * 32 + ln;
    int i_glob = it * 64 + i_loc;

    const short* Qp = Qf + (size_t)bh * NVOX * DE;
    const short* Kp = Kf + (size_t)bh * NVOX * DE;
    const short* Vp = Vf + (size_t)bh * DK * NVOX;

    f16x8 qf[4];
    #pragma unroll
    for (int ks = 0; ks < 4; ks++)
        qf[ks] = *(const f16x8*)&Qp[(size_t)i_glob * DE + ks * 16 + hv * 8];

    float mL = -INFINITY;
    float lsum = 0.f;
    f32x16 O;
    #pragma unroll
    for (int r = 0; r < 16; r++) O[r] = 0.f;

    // staging addresses (fixed per thread)
    int krow0 = t >> 3, kcol = (t & 7) * 8;     // K: 4 chunks of 16 rows
    int vrow0 = t >> 3;                          // V: 2 chunks of 16 rows
    uint4 kr[4], vr[2];

    int jt0 = jp ? 14 : 0, jt1 = jp ? 27 : 14;

    // prologue: stage first tile
    {
        int jb = jt0 * 64;
        #pragma unroll
        for (int q = 0; q < 4; q++)
            kr[q] = *(const uint4*)&Kp[(size_t)(jb + krow0 + q * 16) * DE + kcol];
        #pragma unroll
        for (int q = 0; q < 2; q++)
            vr[q] = *(const uint4*)&Vp[(size_t)(vrow0 + q * 16) * NVOX + jb + kcol];
        #pragma unroll
        for (int q = 0; q < 4; q++)
            *(uint4*)&sm.K[krow0 + q * 16][kcol] = kr[q];
        #pragma unroll
        for (int q = 0; q < 2; q++)
            *(uint4*)&sm.V[vrow0 + q * 16][kcol] = vr[q];
    }

    #pragma unroll 1
    for (int jt = jt0; jt < jt1; jt++) {
        __syncthreads();           // staged tile visible to all waves
        bool more = (jt + 1 < jt1);
        if (more) {                // prefetch next tile into registers
            int jb = (jt + 1) * 64;
            #pragma unroll
            for (int q = 0; q < 4; q++)
                kr[q] = *(const uint4*)&Kp[(size_t)(jb + krow0 + q * 16) * DE + kcol];
            #pragma unroll
            for (int q = 0; q < 2; q++)
                vr[q] = *(const uint4*)&Vp[(size_t)(vrow0 + q * 16) * NVOX + jb + kcol];
        }

        // ---- S^T: two 32x32 j-subtiles ----
        f32x16 sc[2];
        #pragma unroll
        for (int js = 0; js < 2; js++) {
            f32x16 s;
            #pragma unroll
            for (int r = 0; r < 16; r++) s[r] = 0.f;
            #pragma unroll
            for (int ks = 0; ks < 4; ks++) {
                f16x8 kfr = *(const f16x8*)&sm.K[js * 32 + ln][ks * 16 + hv * 8];
                s = mfma32h(kfr, qf[ks], s);
            }
            sc[js] = s;
        }

        // ---- online softmax ----
        float mx = sc[0][0];
        #pragma unroll
        for (int js = 0; js < 2; js++)
            #pragma unroll
            for (int r = 0; r < 16; r++) mx = fmaxf(mx, sc[js][r]);
        mx = fmaxf(mx, __shfl_xor(mx, 32));
        float mLn = fmaxf(mL, mx * LOG2E);
        float alpha = exp2f(mL - mLn);
        mL = mLn;
        float ps = 0.f;
        #pragma unroll
        for (int js = 0; js < 2; js++)
            #pragma unroll
            for (int r = 0; r < 16; r++) {
                float p = exp2f(fmaf(sc[js][r], LOG2E, -mLn));
                sc[js][r] = p;
                ps += p;
            }
        ps += __shfl_xor(ps, 32);
        lsum = lsum * alpha + ps;

        // ---- P: C-layout -> LDS [i][j] f16, packed cvt (wave-private rows) --
        #pragma unroll
        for (int js = 0; js < 2; js++)
            #pragma unroll
            for (int g = 0; g < 4; g++) {
                union { fp16x2 h2[2]; uint2 v; } pk;
                pk.h2[0] = __builtin_amdgcn_cvt_pkrtz(sc[js][4 * g + 0], sc[js][4 * g + 1]);
                pk.h2[1] = __builtin_amdgcn_cvt_pkrtz(sc[js][4 * g + 2], sc[js][4 * g + 3]);
                *(uint2*)&sm.P[i_loc][js * 32 + g * 8 + hv * 4] = pk.v;
            }

        // ---- O^T += Vt * P ----
        #pragma unroll
        for (int r = 0; r < 16; r++) O[r] *= alpha;
        #pragma unroll
        for (int ks = 0; ks < 4; ks++) {
            f16x8 va = *(const f16x8*)&sm.V[ln][ks * 16 + hv * 8];
            f16x8 pb = *(const f16x8*)&sm.P[i_loc][ks * 16 + hv * 8];
            O = mfma32h(va, pb, O);
        }

        __syncthreads();           // all waves done reading K/V
        if (more) {                // commit prefetched tile to LDS
            #pragma unroll
            for (int q = 0; q < 4; q++)
                *(uint4*)&sm.K[krow0 + q * 16][kcol] = kr[q];
            #pragma unroll
            for (int q = 0; q < 2; q++)
                *(uint4*)&sm.V[vrow0 + q * 16][kcol] = vr[q];
        }
    }

    // ---- partial epilogue: f16 unnormalized O^T + (m, l) ----
    short* Op = wsO + ((size_t)jp * (B_ * HEADS) + bh) * DK * NVOX;
    #pragma unroll
    for (int r = 0; r < 16; r++) {
        int d = (r & 3) + 8 * (r >> 2) + 4 * hv;
        _Float16 oh = (_Float16)O[r];
        Op[(size_t)d * NVOX + i_glob] = *(short*)&oh;
    }
    if (hv == 0) {
        size_t mo = ((size_t)jp * (B_ * HEADS) + bh) * NVOX + i_glob;
        wsM[mo] = mL;
        wsL[mo] = lsum;
    }
}

// ---------------------------------------------------------------------------
// Combine the two j-half partials (flash merge identity), 4-wide vectorized.
// ---------------------------------------------------------------------------
__global__ void combine_kernel(const short* __restrict__ wsO,
                               const float* __restrict__ wsM,
                               const float* __restrict__ wsL,
                               float* __restrict__ out) {
    int idx = (blockIdx.x * 256 + threadIdx.x) * 4;   // 1,769,472 total
    int i = idx % NVOX;
    int bh = (idx / NVOX) >> 5;
    const size_t oh = (size_t)B_ * HEADS * DK * NVOX;
    const size_t mh = (size_t)B_ * HEADS * NVOX;
    size_t mo = (size_t)bh * NVOX + i;
    float4 m0 = *(const float4*)&wsM[mo];
    float4 m1 = *(const float4*)&wsM[mh + mo];
    float4 l0 = *(const float4*)&wsL[mo];
    float4 l1 = *(const float4*)&wsL[mh + mo];
    uint2 o0u = *(const uint2*)&wsO[idx];
    uint2 o1u = *(const uint2*)&wsO[oh + idx];
    const short* o0s = (const short*)&o0u;
    const short* o1s = (const short*)&o1u;
    const float* m0p = (const float*)&m0; const float* m1p = (const float*)&m1;
    const float* l0p = (const float*)&l0; const float* l1p = (const float*)&l1;
    float4 res;
    float* rp = (float*)&res;
    #pragma unroll
    for (int j = 0; j < 4; j++) {
        float m = fmaxf(m0p[j], m1p[j]);
        float a0 = exp2f(m0p[j] - m), a1 = exp2f(m1p[j] - m);
        rp[j] = (a0 * h2f(o0s[j]) + a1 * h2f(o1s[j])) /
                (a0 * l0p[j] + a1 * l1p[j]);
    }
    *(float4*)&out[idx] = res;
}

// ---------------------------------------------------------------------------
extern "C" void kernel_launch(void* const* d_in, const int* in_sizes, int n_in,
                              void* d_out, int out_size, void* d_ws, size_t ws_size,
                              hipStream_t stream) {
    const float* x     = (const float*)d_in[0];
    const float* wq    = (const float*)d_in[1];
    const float* bq    = (const float*)d_in[2];
    const float* wk    = (const float*)d_in[3];
    const float* bk    = (const float*)d_in[4];
    const float* wv    = (const float*)d_in[5];
    const float* bv    = (const float*)d_in[6];
    const float* rel_d = (const float*)d_in[7];
    const float* rel_h = (const float*)d_in[8];
    const float* rel_w = (const float*)d_in[9];
    float* out = (float*)d_out;

    size_t qksz = (size_t)B_ * HEADS * NVOX * DE;        // 3,538,944
    size_t vsz  = (size_t)B_ * HEADS * DK * NVOX;        // 1,769,472
    short* Qf  = (short*)d_ws;
    short* Kf  = Qf + qksz;
    short* Vf  = Kf + qksz;
    short* wf  = Vf + vsz;                               // 196,608 shorts
    short* wsO = wf + (size_t)3 * C_ * C_;               // 2*vsz shorts (f16)
    float* wsM = (float*)(wsO + 2 * vsz);                // 2*B*H*NVOX floats
    float* wsL = wsM + 2 * (size_t)B_ * HEADS * NVOX;
    short* xf  = wsO;                                    // aliases wsO (dead before attn)

    prep_kernel<<<dim3(1488), dim3(256), 0, stream>>>(
        x, wq, wk, wv, rel_d, rel_h, rel_w, wf, xf, Qf);
    fproj_kernel<<<dim3(NVOX / 64, HEADS, B_), dim3(384), 0, stream>>>(
        xf, wf, bq, bk, bv, Qf, Kf, Vf);
    attn_kernel<<<dim3(2 * NVOX / 64, HEADS, B_), dim3(128), 0, stream>>>(
        Qf, Kf, Vf, wsO, wsM, wsL);
    combine_kernel<<<dim3((int)(vsz / 1024)), dim3(256), 0, stream>>>(wsO, wsM, wsL, out);
}

// Round 13
// 177.486 us; speedup vs baseline: 2.0726x; 1.0569x over previous
//
#include <hip/hip_runtime.h>
#include <math.h>

#define HEADS 8
#define DK 32
#define B_ 4
#define C_ 256
#define NVOX 1728   // 12*12*12
#define DE 64       // effective head dim: Q'=[q;pos], K'=[k;q]
#define PITCH 72    // attn LDS pitch (shorts): 144 B rows
#define XPITCH 136  // fproj x-chunk LDS pitch (shorts): 272 B rows
#define CPITCH 36   // fproj cbuf pitch (floats)
#define LOG2E 1.44269504088896f

typedef _Float16 f16x8 __attribute__((ext_vector_type(8)));
typedef __fp16 fp16x2 __attribute__((ext_vector_type(2)));
typedef float f32x16 __attribute__((ext_vector_type(16)));

__device__ inline float h2f(short s) {
    _Float16 h = *(_Float16*)&s;
    return (float)h;
}
__device__ inline f32x16 mfma32h(f16x8 a, f16x8 b, f32x16 c) {
    return __builtin_amdgcn_mfma_f32_32x32x16_f16(a, b, c, 0, 0, 0);
}

union HF8 { _Float16 h[8]; f16x8 f; uint4 v; };

// ---------------------------------------------------------------------------
// Mega-fused projection: x fp32 (in-kernel transpose+cvt), w fp32 (in-reg
// cvt), pos fused in epilogue.  out: Qf (with pos upper), Kf ([k;q]), Vf.
// grid (27, HEADS, B_), block 384 = 6 waves = 3 mats x 2 n-halves.
// ---------------------------------------------------------------------------
struct FS {
    union {
        short xs[64 * XPITCH];       // f16 x-chunk, [n][c_local<128]
        float cbuf[3][64][CPITCH];   // epilogue C staging [mat][n][o]
    } u;
};

__global__ __launch_bounds__(384, 3)
void fproj_kernel(const float* __restrict__ x,
                  const float* __restrict__ wq, const float* __restrict__ wk,
                  const float* __restrict__ wv,
                  const float* __restrict__ bq, const float* __restrict__ bk,
                  const float* __restrict__ bv,
                  const float* __restrict__ rel_d, const float* __restrict__ rel_h,
                  const float* __restrict__ rel_w,
                  short* __restrict__ Qf, short* __restrict__ Kf,
                  short* __restrict__ Vf) {
    __shared__ FS sm;
    int nb = blockIdx.x * 64, h = blockIdx.y, b = blockIdx.z;
    int bh = b * HEADS + h;
    int t = threadIdx.x;
    int w = t >> 6, l = t & 63, ln = l & 31, hv = l >> 5;
    int mat = w >> 1, nh = w & 1;

    const float* xb = x + (size_t)b * C_ * NVOX + nb;   // [c][n-slice]
    const float* wsel = (mat == 0) ? wq : (mat == 1) ? wk : wv;
    const float* wrow = wsel + (size_t)(h * DK + ln) * C_;
    int xrow = (nh * 32 + ln) * XPITCH;

    f32x16 acc;
    #pragma unroll
    for (int r = 0; r < 16; r++) acc[r] = 0.f;

    #pragma unroll 1
    for (int ch = 0; ch < 2; ch++) {
        // ---- W fragments for this chunk: fp32 -> f16 in registers ----
        f16x8 wfr[8];
        #pragma unroll
        for (int ks = 0; ks < 8; ks++) {
            const float* wp = wrow + ch * 128 + ks * 16 + hv * 8;
            float4 a4 = *(const float4*)&wp[0];
            float4 b4 = *(const float4*)&wp[4];
            HF8 hh;
            hh.h[0] = (_Float16)a4.x; hh.h[1] = (_Float16)a4.y;
            hh.h[2] = (_Float16)a4.z; hh.h[3] = (_Float16)a4.w;
            hh.h[4] = (_Float16)b4.x; hh.h[5] = (_Float16)b4.y;
            hh.h[6] = (_Float16)b4.z; hh.h[7] = (_Float16)b4.w;
            wfr[ks] = hh.f;
        }

        // ---- stage x chunk: load [c][n] fp32 coalesced, write transposed f16
        __syncthreads();   // previous chunk fully consumed
        for (int e = t; e < 2048; e += 384) {
            int cl = e >> 4;              // 0..127 (c within chunk)
            int n4 = (e & 15) * 4;        // 0..60
            float4 v = *(const float4*)&xb[(size_t)(ch * 128 + cl) * NVOX + n4];
            _Float16 h0 = (_Float16)v.x, h1 = (_Float16)v.y,
                     h2 = (_Float16)v.z, h3 = (_Float16)v.w;
            sm.u.xs[(n4 + 0) * XPITCH + cl] = *(short*)&h0;
            sm.u.xs[(n4 + 1) * XPITCH + cl] = *(short*)&h1;
            sm.u.xs[(n4 + 2) * XPITCH + cl] = *(short*)&h2;
            sm.u.xs[(n4 + 3) * XPITCH + cl] = *(short*)&h3;
        }
        __syncthreads();

        #pragma unroll
        for (int ks = 0; ks < 8; ks++) {
            f16x8 bfr = *(const f16x8*)&sm.u.xs[xrow + ks * 16 + hv * 8];
            acc = mfma32h(wfr[ks], bfr, acc);
        }
    }
    __syncthreads();   // x tile dead; reuse as cbuf

    const float* bias = (mat == 0) ? bq : (mat == 1) ? bk : bv;
    int ncol = nh * 32 + ln;
    #pragma unroll
    for (int q2 = 0; q2 < 4; q2++) {
        float4 cv;
        float* cvp = (float*)&cv;
        #pragma unroll
        for (int m = 0; m < 4; m++) {
            int o_loc = 8 * q2 + 4 * hv + m;
            cvp[m] = acc[4 * q2 + m] + bias[h * DK + o_loc];
        }
        *(float4*)&sm.u.cbuf[mat][ncol][8 * q2 + 4 * hv] = cv;
    }
    __syncthreads();

    if (t < 256) {
        // ---- readout q/k ----
        {
            int n = t >> 2, ddg = (t & 3) * 8;
            size_t rowoff = ((size_t)bh * NVOX + nb + n) * DE;
            HF8 qh, kh;
            #pragma unroll
            for (int j = 0; j < 8; j++) {
                qh.h[j] = (_Float16)sm.u.cbuf[0][n][ddg + j];
                kh.h[j] = (_Float16)sm.u.cbuf[1][n][ddg + j];
            }
            *(uint4*)&Qf[rowoff + ddg] = qh.v;
            *(uint4*)&Kf[rowoff + ddg] = kh.v;
            *(uint4*)&Kf[rowoff + DK + ddg] = qh.v;   // K' upper = q
        }
        // ---- readout v ----
        {
            int d = t >> 3, ng = (t & 7) * 8;
            HF8 vv;
            #pragma unroll
            for (int j = 0; j < 8; j++)
                vv.h[j] = (_Float16)sm.u.cbuf[2][ng + j][d];
            *(uint4*)&Vf[((size_t)bh * DK + d) * NVOX + nb + ng] = vv.v;
        }
        // ---- pos -> Q' upper half [32:64) ----
        {
            int nl = t & 63, dd0 = (t >> 6) * 8;
            int n = nb + nl;
            int di = n / 144, wi = (n / 12) % 12, hi = n % 12;
            HF8 ph;
            #pragma unroll
            for (int o = 0; o < 8; o++) {
                int hd = h * DK + dd0 + o;
                ph.h[o] = (_Float16)(rel_d[hd * 12 + di] + rel_w[hd * 12 + wi] +
                                     rel_h[hd * 12 + hi]);
            }
            *(uint4*)&Qf[((size_t)bh * NVOX + n) * DE + DK + dd0] = ph.v;
        }
    }
}

// ---------------------------------------------------------------------------
// Flash attention partial (R10 structure): 32x32x16 f16 MFMA, S^T orientation,
// i-tile 64 (2 waves), j-split 2.  grid (54, HEADS, B_), block 128.
// LDS 23.0 KB -> 6 blocks/CU.
// ---------------------------------------------------------------------------
struct SMem {
    short K[64][PITCH];
    short V[DK][PITCH];
    short P[64][PITCH];
};

__global__ __launch_bounds__(128, 3)
void attn_kernel(const short* __restrict__ Qf, const short* __restrict__ Kf,
                 const short* __restrict__ Vf,
                 short* __restrict__ wsO, float* __restrict__ wsM,
                 float* __restrict__ wsL) {
    __shared__ SMem sm;
    int bx = blockIdx.x;
    int it = bx >> 1, jp = bx & 1;
    int h = blockIdx.y, b = blockIdx.z;
    int bh = b * HEADS + h;
    int t = threadIdx.x;
    int w  = t >> 6;
    int l  = t & 63;
    int ln = l & 31;
    int hv = l >> 5;
    int i_loc  = w * 32 + ln;
    int i_glob = it * 64 + i_loc;

    const short* Qp = Qf + (size_t)bh * NVOX * DE;
    const short* Kp = Kf + (size_t)bh * NVOX * DE;
    const short* Vp = Vf + (size_t)bh * DK * NVOX;

    f16x8 qf[4];
    #pragma unroll
    for (int ks = 0; ks < 4; ks++)
        qf[ks] = *(const f16x8*)&Qp[(size_t)i_glob * DE + ks * 16 + hv * 8];

    float mL = -INFINITY;
    float lsum = 0.f;
    f32x16 O;
    #pragma unroll
    for (int r = 0; r < 16; r++) O[r] = 0.f;

    int jt0 = jp ? 14 : 0, jt1 = jp ? 27 : 14;
    #pragma unroll 1
    for (int jt = jt0; jt < jt1; jt++) {
        int jb = jt * 64;
        __syncthreads();
        for (int e = t; e < 512; e += 128) {
            int row = e >> 3, c = (e & 7) * 8;
            *(uint4*)&sm.K[row][c] = *(const uint4*)&Kp[(size_t)(jb + row) * DE + c];
        }
        for (int e = t; e < 256; e += 128) {
            int d = e >> 3, c = (e & 7) * 8;
            *(uint4*)&sm.V[d][c] = *(const uint4*)&Vp[(size_t)d * NVOX + jb + c];
        }
        __syncthreads();

        // ---- S^T: two 32x32 j-subtiles ----
        f32x16 sc[2];
        #pragma unroll
        for (int js = 0; js < 2; js++) {
            f32x16 s;
            #pragma unroll
            for (int r = 0; r < 16; r++) s[r] = 0.f;
            #pragma unroll
            for (int ks = 0; ks < 4; ks++) {
                f16x8 kfr = *(const f16x8*)&sm.K[js * 32 + ln][ks * 16 + hv * 8];
                s = mfma32h(kfr, qf[ks], s);
            }
            sc[js] = s;
        }

        // ---- online softmax ----
        float mx = sc[0][0];
        #pragma unroll
        for (int js = 0; js < 2; js++)
            #pragma unroll
            for (int r = 0; r < 16; r++) mx = fmaxf(mx, sc[js][r]);
        mx = fmaxf(mx, __shfl_xor(mx, 32));
        float mLn = fmaxf(mL, mx * LOG2E);
        float alpha = exp2f(mL - mLn);
        mL = mLn;
        float ps = 0.f;
        #pragma unroll
        for (int js = 0; js < 2; js++)
            #pragma unroll
            for (int r = 0; r < 16; r++) {
                float p = exp2f(fmaf(sc[js][r], LOG2E, -mLn));
                sc[js][r] = p;
                ps += p;
            }
        ps += __shfl_xor(ps, 32);
        lsum = lsum * alpha + ps;

        // ---- P: C-layout -> LDS [i][j] f16, packed cvt ----
        #pragma unroll
        for (int js = 0; js < 2; js++)
            #pragma unroll
            for (int g = 0; g < 4; g++) {
                union { fp16x2 h2[2]; uint2 v; } pk;
                pk.h2[0] = __builtin_amdgcn_cvt_pkrtz(sc[js][4 * g + 0], sc[js][4 * g + 1]);
                pk.h2[1] = __builtin_amdgcn_cvt_pkrtz(sc[js][4 * g + 2], sc[js][4 * g + 3]);
                *(uint2*)&sm.P[i_loc][js * 32 + g * 8 + hv * 4] = pk.v;
            }

        // ---- O^T += Vt * P ----
        #pragma unroll
        for (int r = 0; r < 16; r++) O[r] *= alpha;
        #pragma unroll
        for (int ks = 0; ks < 4; ks++) {
            f16x8 va = *(const f16x8*)&sm.V[ln][ks * 16 + hv * 8];
            f16x8 pb = *(const f16x8*)&sm.P[i_loc][ks * 16 + hv * 8];
            O = mfma32h(va, pb, O);
        }
    }

    // ---- partial epilogue: f16 unnormalized O^T + (m, l) ----
    short* Op = wsO + ((size_t)jp * (B_ * HEADS) + bh) * DK * NVOX;
    #pragma unroll
    for (int r = 0; r < 16; r++) {
        int d = (r & 3) + 8 * (r >> 2) + 4 * hv;
        _Float16 oh = (_Float16)O[r];
        Op[(size_t)d * NVOX + i_glob] = *(short*)&oh;
    }
    if (hv == 0) {
        size_t mo = ((size_t)jp * (B_ * HEADS) + bh) * NVOX + i_glob;
        wsM[mo] = mL;
        wsL[mo] = lsum;
    }
}

// ---------------------------------------------------------------------------
// Combine the two j-half partials (flash merge identity), 4-wide vectorized.
// ---------------------------------------------------------------------------
__global__ void combine_kernel(const short* __restrict__ wsO,
                               const float* __restrict__ wsM,
                               const float* __restrict__ wsL,
                               float* __restrict__ out) {
    int idx = (blockIdx.x * 256 + threadIdx.x) * 4;   // 1,769,472 total
    int i = idx % NVOX;
    int bh = (idx / NVOX) >> 5;
    const size_t oh = (size_t)B_ * HEADS * DK * NVOX;
    const size_t mh = (size_t)B_ * HEADS * NVOX;
    size_t mo = (size_t)bh * NVOX + i;
    float4 m0 = *(const float4*)&wsM[mo];
    float4 m1 = *(const float4*)&wsM[mh + mo];
    float4 l0 = *(const float4*)&wsL[mo];
    float4 l1 = *(const float4*)&wsL[mh + mo];
    uint2 o0u = *(const uint2*)&wsO[idx];
    uint2 o1u = *(const uint2*)&wsO[oh + idx];
    const short* o0s = (const short*)&o0u;
    const short* o1s = (const short*)&o1u;
    const float* m0p = (const float*)&m0; const float* m1p = (const float*)&m1;
    const float* l0p = (const float*)&l0; const float* l1p = (const float*)&l1;
    float4 res;
    float* rp = (float*)&res;
    #pragma unroll
    for (int j = 0; j < 4; j++) {
        float m = fmaxf(m0p[j], m1p[j]);
        float a0 = exp2f(m0p[j] - m), a1 = exp2f(m1p[j] - m);
        rp[j] = (a0 * h2f(o0s[j]) + a1 * h2f(o1s[j])) /
                (a0 * l0p[j] + a1 * l1p[j]);
    }
    *(float4*)&out[idx] = res;
}

// ---------------------------------------------------------------------------
extern "C" void kernel_launch(void* const* d_in, const int* in_sizes, int n_in,
                              void* d_out, int out_size, void* d_ws, size_t ws_size,
                              hipStream_t stream) {
    const float* x     = (const float*)d_in[0];
    const float* wq    = (const float*)d_in[1];
    const float* bq    = (const float*)d_in[2];
    const float* wk    = (const float*)d_in[3];
    const float* bk    = (const float*)d_in[4];
    const float* wv    = (const float*)d_in[5];
    const float* bv    = (const float*)d_in[6];
    const float* rel_d = (const float*)d_in[7];
    const float* rel_h = (const float*)d_in[8];
    const float* rel_w = (const float*)d_in[9];
    float* out = (float*)d_out;

    size_t qksz = (size_t)B_ * HEADS * NVOX * DE;        // 3,538,944
    size_t vsz  = (size_t)B_ * HEADS * DK * NVOX;        // 1,769,472
    short* Qf  = (short*)d_ws;
    short* Kf  = Qf + qksz;
    short* Vf  = Kf + qksz;
    short* wsO = Vf + vsz;                               // 2*vsz shorts (f16)
    float* wsM = (float*)(wsO + 2 * vsz);                // 2*B*H*NVOX floats
    float* wsL = wsM + 2 * (size_t)B_ * HEADS * NVOX;

    fproj_kernel<<<dim3(NVOX / 64, HEADS, B_), dim3(384), 0, stream>>>(
        x, wq, wk, wv, bq, bk, bv, rel_d, rel_h, rel_w, Qf, Kf, Vf);
    attn_kernel<<<dim3(2 * NVOX / 64, HEADS, B_), dim3(128), 0, stream>>>(
        Qf, Kf, Vf, wsO, wsM, wsL);
    combine_kernel<<<dim3((int)(vsz / 1024)), dim3(256), 0, stream>>>(wsO, wsM, wsL, out);
}

// Round 14
// 158.905 us; speedup vs baseline: 2.3150x; 1.1169x over previous
//
#include <hip/hip_runtime.h>
#include <math.h>

#define HEADS 8
#define DK 32
#define B_ 4
#define C_ 256
#define NVOX 1728   // 12*12*12
#define DE 64       // effective head dim: Q'=[q;pos], K'=[k;q]
#define PITCH 72    // attn LDS pitch (shorts): 144 B rows
#define XPITCH 136  // fproj x-chunk LDS pitch (shorts)
#define CPITCH 36   // fproj cbuf pitch (floats)
#define LOG2E 1.44269504088896f

typedef _Float16 f16x8 __attribute__((ext_vector_type(8)));
typedef __fp16 fp16x2 __attribute__((ext_vector_type(2)));
typedef float f32x16 __attribute__((ext_vector_type(16)));

__device__ inline float h2f(short s) {
    _Float16 h = *(_Float16*)&s;
    return (float)h;
}
__device__ inline f32x16 mfma32h(f16x8 a, f16x8 b, f32x16 c) {
    return __builtin_amdgcn_mfma_f32_32x32x16_f16(a, b, c, 0, 0, 0);
}

union H8 { _Float16 h[8]; uint4 v; };
union H4 { _Float16 h[4]; uint2 v; };

// ---------------------------------------------------------------------------
// Fused prep: [0,192) w->f16 x4 | [192,624) x transpose->f16 | [624,1488) pos
// ---------------------------------------------------------------------------
__global__ __launch_bounds__(256)
void prep_kernel(const float* __restrict__ x,
                 const float* __restrict__ wq, const float* __restrict__ wk,
                 const float* __restrict__ wv,
                 const float* __restrict__ rel_d, const float* __restrict__ rel_h,
                 const float* __restrict__ rel_w,
                 short* __restrict__ wf, short* __restrict__ xf,
                 short* __restrict__ Qf) {
    __shared__ float tile[64][65];
    int bid = blockIdx.x;
    int t = threadIdx.x;

    if (bid < 192) {                       // ---- weights -> f16 (x4) ----
        int idx = (bid * 256 + t) * 4;     // 3*65536 total
        int m = idx >> 16;
        const float* w = (m == 0) ? wq : (m == 1) ? wk : wv;
        float4 v = *(const float4*)&w[idx & 65535];
        H4 hh;
        hh.h[0] = (_Float16)v.x; hh.h[1] = (_Float16)v.y;
        hh.h[2] = (_Float16)v.z; hh.h[3] = (_Float16)v.w;
        *(uint2*)&wf[idx] = hh.v;
    } else if (bid < 624) {                // ---- x[b][c][n] -> xf[b][n][c] ----
        int q = bid - 192;                 // 432 blocks: (27, 4, 4)
        int nb = (q % 27) * 64;
        int c0 = ((q / 27) % 4) * 64;
        int b  = q / 108;
        const float* xb = x + (size_t)b * C_ * NVOX;
        for (int e = t; e < 4096; e += 256) {
            int ci = e >> 6, nl = e & 63;
            tile[ci][nl] = xb[(size_t)(c0 + ci) * NVOX + nb + nl];
        }
        __syncthreads();
        for (int e = t; e < 512; e += 256) {
            int n = e >> 3, cg = (e & 7) * 8;
            H8 hi;
            #pragma unroll
            for (int j = 0; j < 8; j++) hi.h[j] = (_Float16)tile[cg + j][n];
            *(uint4*)&xf[((size_t)b * NVOX + nb + n) * C_ + c0 + cg] = hi.v;
        }
    } else {                               // ---- pos -> Q' upper half ----
        int q = bid - 624;                 // 864 blocks: (27, 8, 4)
        int nb = (q % 27) * 64;
        int h  = (q / 27) % 8;
        int b  = q / 216;
        int bh = b * HEADS + h;
        int nl = t & 63, dd0 = (t >> 6) * 8;
        int n = nb + nl;
        int di = n / 144, wi = (n / 12) % 12, hi = n % 12;
        H8 ph;
        #pragma unroll
        for (int o = 0; o < 8; o++) {
            int hd = h * DK + dd0 + o;
            ph.h[o] = (_Float16)(rel_d[hd * 12 + di] + rel_w[hd * 12 + wi] +
                                 rel_h[hd * 12 + hi]);
        }
        *(uint4*)&Qf[((size_t)bh * NVOX + n) * DE + DK + dd0] = ph.v;
    }
}

// ---------------------------------------------------------------------------
// MFMA projection (f16), K chunked 2x128.  grid (27, HEADS, B_), block 384.
// Kf is 32-wide (k only); attn reads K' upper half (=q) from Qf.
// ---------------------------------------------------------------------------
struct FS {
    union {
        short xs[64 * XPITCH];
        float cbuf[3][64][CPITCH];
    } u;
};

__global__ __launch_bounds__(384, 4)
void fproj_kernel(const short* __restrict__ xf, const short* __restrict__ wf,
                  const float* __restrict__ bq, const float* __restrict__ bk,
                  const float* __restrict__ bv,
                  short* __restrict__ Qf, short* __restrict__ Kf,
                  short* __restrict__ Vf) {
    __shared__ FS sm;
    int nb = blockIdx.x * 64, h = blockIdx.y, b = blockIdx.z;
    int bh = b * HEADS + h;
    int t = threadIdx.x;
    int w = t >> 6, l = t & 63, ln = l & 31, hv = l >> 5;
    int mat = w >> 1, nh = w & 1;

    const short* xb = xf + ((size_t)b * NVOX + nb) * C_;
    const short* wA = wf + ((size_t)mat * C_ + h * DK + ln) * C_;
    int xrow = (nh * 32 + ln) * XPITCH;

    f32x16 acc;
    #pragma unroll
    for (int r = 0; r < 16; r++) acc[r] = 0.f;

    #pragma unroll 1
    for (int ch = 0; ch < 2; ch++) {
        __syncthreads();
        for (int e = t; e < 1024; e += 384) {
            int row = e >> 4, c8 = (e & 15) * 8;
            *(uint4*)&sm.u.xs[row * XPITCH + c8] =
                *(const uint4*)&xb[row * C_ + ch * 128 + c8];
        }
        __syncthreads();
        #pragma unroll 4
        for (int ks = 0; ks < 8; ks++) {
            int kl_ = ks * 16 + hv * 8;
            f16x8 a = *(const f16x8*)&wA[ch * 128 + kl_];
            f16x8 bfr = *(const f16x8*)&sm.u.xs[xrow + kl_];
            acc = mfma32h(a, bfr, acc);
        }
    }
    __syncthreads();   // x tile dead; reuse as cbuf

    const float* bias = (mat == 0) ? bq : (mat == 1) ? bk : bv;
    int ncol = nh * 32 + ln;
    #pragma unroll
    for (int q2 = 0; q2 < 4; q2++) {
        float4 cv;
        float* cvp = (float*)&cv;
        #pragma unroll
        for (int m = 0; m < 4; m++) {
            int o_loc = 8 * q2 + 4 * hv + m;
            cvp[m] = acc[4 * q2 + m] + bias[h * DK + o_loc];
        }
        *(float4*)&sm.u.cbuf[mat][ncol][8 * q2 + 4 * hv] = cv;
    }
    __syncthreads();

    if (t < 256) {                          // ---- readout q/k ----
        int n = t >> 2, ddg = (t & 3) * 8;
        H8 qh, kh;
        #pragma unroll
        for (int j = 0; j < 8; j++) {
            qh.h[j] = (_Float16)sm.u.cbuf[0][n][ddg + j];
            kh.h[j] = (_Float16)sm.u.cbuf[1][n][ddg + j];
        }
        *(uint4*)&Qf[((size_t)bh * NVOX + nb + n) * DE + ddg] = qh.v;
        *(uint4*)&Kf[((size_t)bh * NVOX + nb + n) * DK + ddg] = kh.v;
    }
    if (t < 256) {                          // ---- readout v ----
        int d = t >> 3, ng = (t & 7) * 8;
        H8 vv;
        #pragma unroll
        for (int j = 0; j < 8; j++)
            vv.h[j] = (_Float16)sm.u.cbuf[2][ng + j][d];
        *(uint4*)&Vf[((size_t)bh * DK + d) * NVOX + nb + ng] = vv.v;
    }
}

// ---------------------------------------------------------------------------
// Flash attention partial (R10 structure): 32x32x16 f16 MFMA, S^T orientation,
// i-tile 64 (2 waves), j-split 2.  grid (54, HEADS, B_), block 128.
// K' staged from Kf (lower 32 cols = k) + Qf (upper 32 cols = q).
// ---------------------------------------------------------------------------
struct SMem {
    short K[64][PITCH];
    short V[DK][PITCH];
    short P[64][PITCH];
};

__global__ __launch_bounds__(128, 3)
void attn_kernel(const short* __restrict__ Qf, const short* __restrict__ Kf,
                 const short* __restrict__ Vf,
                 short* __restrict__ wsO, float* __restrict__ wsM,
                 float* __restrict__ wsL) {
    __shared__ SMem sm;
    int bx = blockIdx.x;
    int it = bx >> 1, jp = bx & 1;
    int h = blockIdx.y, b = blockIdx.z;
    int bh = b * HEADS + h;
    int t = threadIdx.x;
    int w  = t >> 6;
    int l  = t & 63;
    int ln = l & 31;
    int hv = l >> 5;
    int i_loc  = w * 32 + ln;
    int i_glob = it * 64 + i_loc;

    const short* Qp = Qf + (size_t)bh * NVOX * DE;
    const short* Kp = Kf + (size_t)bh * NVOX * DK;
    const short* Vp = Vf + (size_t)bh * DK * NVOX;

    f16x8 qf[4];
    #pragma unroll
    for (int ks = 0; ks < 4; ks++)
        qf[ks] = *(const f16x8*)&Qp[(size_t)i_glob * DE + ks * 16 + hv * 8];

    float mL = -INFINITY;
    float lsum = 0.f;
    f32x16 O;
    #pragma unroll
    for (int r = 0; r < 16; r++) O[r] = 0.f;

    int jt0 = jp ? 14 : 0, jt1 = jp ? 27 : 14;
    #pragma unroll 1
    for (int jt = jt0; jt < jt1; jt++) {
        int jb = jt * 64;
        __syncthreads();
        for (int e = t; e < 512; e += 128) {
            int row = e >> 3, cq = e & 7, c8 = cq * 8;
            uint4 v = (cq < 4)
                ? *(const uint4*)&Kp[(size_t)(jb + row) * DK + c8]
                : *(const uint4*)&Qp[(size_t)(jb + row) * DE + (c8 - 32)];
            *(uint4*)&sm.K[row][c8] = v;
        }
        for (int e = t; e < 256; e += 128) {
            int d = e >> 3, c = (e & 7) * 8;
            *(uint4*)&sm.V[d][c] = *(const uint4*)&Vp[(size_t)d * NVOX + jb + c];
        }
        __syncthreads();

        // ---- S^T: two 32x32 j-subtiles ----
        f32x16 sc[2];
        #pragma unroll
        for (int js = 0; js < 2; js++) {
            f32x16 s;
            #pragma unroll
            for (int r = 0; r < 16; r++) s[r] = 0.f;
            #pragma unroll
            for (int ks = 0; ks < 4; ks++) {
                f16x8 kfr = *(const f16x8*)&sm.K[js * 32 + ln][ks * 16 + hv * 8];
                s = mfma32h(kfr, qf[ks], s);
            }
            sc[js] = s;
        }

        // ---- online softmax ----
        float mx = sc[0][0];
        #pragma unroll
        for (int js = 0; js < 2; js++)
            #pragma unroll
            for (int r = 0; r < 16; r++) mx = fmaxf(mx, sc[js][r]);
        mx = fmaxf(mx, __shfl_xor(mx, 32));
        float mLn = fmaxf(mL, mx * LOG2E);
        float alpha = exp2f(mL - mLn);
        mL = mLn;
        float ps = 0.f;
        #pragma unroll
        for (int js = 0; js < 2; js++)
            #pragma unroll
            for (int r = 0; r < 16; r++) {
                float p = exp2f(fmaf(sc[js][r], LOG2E, -mLn));
                sc[js][r] = p;
                ps += p;
            }
        ps += __shfl_xor(ps, 32);
        lsum = lsum * alpha + ps;

        // ---- P: C-layout -> LDS [i][j] f16, packed cvt ----
        #pragma unroll
        for (int js = 0; js < 2; js++)
            #pragma unroll
            for (int g = 0; g < 4; g++) {
                union { fp16x2 h2[2]; uint2 v; } pk;
                pk.h2[0] = __builtin_amdgcn_cvt_pkrtz(sc[js][4 * g + 0], sc[js][4 * g + 1]);
                pk.h2[1] = __builtin_amdgcn_cvt_pkrtz(sc[js][4 * g + 2], sc[js][4 * g + 3]);
                *(uint2*)&sm.P[i_loc][js * 32 + g * 8 + hv * 4] = pk.v;
            }

        // ---- O^T += Vt * P ----
        #pragma unroll
        for (int r = 0; r < 16; r++) O[r] *= alpha;
        #pragma unroll
        for (int ks = 0; ks < 4; ks++) {
            f16x8 va = *(const f16x8*)&sm.V[ln][ks * 16 + hv * 8];
            f16x8 pb = *(const f16x8*)&sm.P[i_loc][ks * 16 + hv * 8];
            O = mfma32h(va, pb, O);
        }
    }

    // ---- partial epilogue: f16 unnormalized O^T + (m, l) ----
    short* Op = wsO + ((size_t)jp * (B_ * HEADS) + bh) * DK * NVOX;
    #pragma unroll
    for (int r = 0; r < 16; r++) {
        int d = (r & 3) + 8 * (r >> 2) + 4 * hv;
        _Float16 oh = (_Float16)O[r];
        Op[(size_t)d * NVOX + i_glob] = *(short*)&oh;
    }
    if (hv == 0) {
        size_t mo = ((size_t)jp * (B_ * HEADS) + bh) * NVOX + i_glob;
        wsM[mo] = mL;
        wsL[mo] = lsum;
    }
}

// ---------------------------------------------------------------------------
// Combine the two j-half partials (flash merge identity), 4-wide vectorized.
// ---------------------------------------------------------------------------
__global__ void combine_kernel(const short* __restrict__ wsO,
                               const float* __restrict__ wsM,
                               const float* __restrict__ wsL,
                               float* __restrict__ out) {
    int idx = (blockIdx.x * 256 + threadIdx.x) * 4;   // 1,769,472 total
    int i = idx % NVOX;
    int bh = (idx / NVOX) >> 5;
    const size_t oh = (size_t)B_ * HEADS * DK * NVOX;
    const size_t mh = (size_t)B_ * HEADS * NVOX;
    size_t mo = (size_t)bh * NVOX + i;
    float4 m0 = *(const float4*)&wsM[mo];
    float4 m1 = *(const float4*)&wsM[mh + mo];
    float4 l0 = *(const float4*)&wsL[mo];
    float4 l1 = *(const float4*)&wsL[mh + mo];
    uint2 o0u = *(const uint2*)&wsO[idx];
    uint2 o1u = *(const uint2*)&wsO[oh + idx];
    const short* o0s = (const short*)&o0u;
    const short* o1s = (const short*)&o1u;
    const float* m0p = (const float*)&m0; const float* m1p = (const float*)&m1;
    const float* l0p = (const float*)&l0; const float* l1p = (const float*)&l1;
    float4 res;
    float* rp = (float*)&res;
    #pragma unroll
    for (int j = 0; j < 4; j++) {
        float m = fmaxf(m0p[j], m1p[j]);
        float a0 = exp2f(m0p[j] - m), a1 = exp2f(m1p[j] - m);
        rp[j] = (a0 * h2f(o0s[j]) + a1 * h2f(o1s[j])) /
                (a0 * l0p[j] + a1 * l1p[j]);
    }
    *(float4*)&out[idx] = res;
}

// ---------------------------------------------------------------------------
extern "C" void kernel_launch(void* const* d_in, const int* in_sizes, int n_in,
                              void* d_out, int out_size, void* d_ws, size_t ws_size,
                              hipStream_t stream) {
    const float* x     = (const float*)d_in[0];
    const float* wq    = (const float*)d_in[1];
    const float* bq    = (const float*)d_in[2];
    const float* wk    = (const float*)d_in[3];
    const float* bk    = (const float*)d_in[4];
    const float* wv    = (const float*)d_in[5];
    const float* bv    = (const float*)d_in[6];
    const float* rel_d = (const float*)d_in[7];
    const float* rel_h = (const float*)d_in[8];
    const float* rel_w = (const float*)d_in[9];
    float* out = (float*)d_out;

    size_t qksz = (size_t)B_ * HEADS * NVOX * DE;        // 3,538,944
    size_t vsz  = (size_t)B_ * HEADS * DK * NVOX;        // 1,769,472
    short* Qf  = (short*)d_ws;
    short* Kf  = Qf + qksz;                              // 32-wide: vsz shorts
    short* Vf  = Kf + vsz;
    short* wf  = Vf + vsz;                               // 196,608 shorts
    short* wsO = wf + (size_t)3 * C_ * C_;               // 2*vsz shorts (f16)
    float* wsM = (float*)(wsO + 2 * vsz);                // 2*B*H*NVOX floats
    float* wsL = wsM + 2 * (size_t)B_ * HEADS * NVOX;
    short* xf  = wsO;                                    // aliases wsO (dead before attn)

    prep_kernel<<<dim3(1488), dim3(256), 0, stream>>>(
        x, wq, wk, wv, rel_d, rel_h, rel_w, wf, xf, Qf);
    fproj_kernel<<<dim3(NVOX / 64, HEADS, B_), dim3(384), 0, stream>>>(
        xf, wf, bq, bk, bv, Qf, Kf, Vf);
    attn_kernel<<<dim3(2 * NVOX / 64, HEADS, B_), dim3(128), 0, stream>>>(
        Qf, Kf, Vf, wsO, wsM, wsL);
    combine_kernel<<<dim3((int)(vsz / 1024)), dim3(256), 0, stream>>>(wsO, wsM, wsL, out);
}